// Round 1
// baseline (129.505 us; speedup 1.0000x reference)
//
#include <hip/hip_runtime.h>

#define TAKT 700
#define B 32
#define T 1024
#define V 1024

// ---------------- Kernel 1: per-row log-softmax CE term + argmax ----------------
// One 256-thread block per (b,t) row of V=1024 floats. float4 loads: 4 elems/thread.
__global__ __launch_bounds__(256) void row_kernel(const float* __restrict__ logits,
                                                  const int* __restrict__ tgt,
                                                  float* __restrict__ rowloss,
                                                  int* __restrict__ pred) {
    const int row = blockIdx.x;      // 0..B*T-1
    const int tid = threadIdx.x;     // 0..255
    const float4 v = reinterpret_cast<const float4*>(logits + (size_t)row * V)[tid];

    // thread-local max + first index
    float m = v.x; int mi = tid * 4;
    if (v.y > m) { m = v.y; mi = tid * 4 + 1; }
    if (v.z > m) { m = v.z; mi = tid * 4 + 2; }
    if (v.w > m) { m = v.w; mi = tid * 4 + 3; }

    __shared__ float smax[256];
    __shared__ int   sidx[256];
    __shared__ float ssum[256];
    __shared__ float s_xt;

    smax[tid] = m; sidx[tid] = mi;

    // stash x[tgt] (the thread owning that element)
    const int tg = tgt[row];
    if ((tg >> 2) == tid) {
        const int r = tg & 3;
        s_xt = (r == 0) ? v.x : (r == 1) ? v.y : (r == 2) ? v.z : v.w;
    }
    __syncthreads();

    // deterministic tree reduce for (max, min-index-at-max)
    for (int off = 128; off > 0; off >>= 1) {
        if (tid < off) {
            const float om = smax[tid + off]; const int oi = sidx[tid + off];
            if (om > smax[tid] || (om == smax[tid] && oi < sidx[tid])) {
                smax[tid] = om; sidx[tid] = oi;
            }
        }
        __syncthreads();
    }
    const float rowmax = smax[0];

    ssum[tid] = expf(v.x - rowmax) + expf(v.y - rowmax) +
                expf(v.z - rowmax) + expf(v.w - rowmax);
    __syncthreads();
    for (int off = 128; off > 0; off >>= 1) {
        if (tid < off) ssum[tid] += ssum[tid + off];
        __syncthreads();
    }

    if (tid == 0) {
        const float logZ = logf(ssum[0]);
        rowloss[row] = -(s_xt - rowmax - logZ);
        pred[row]    = sidx[0];
    }
}

// ---------------- Kernel 2: overlap penalty ----------------
// grid = B*8 blocks: block (b, chunk). Each block rebuilds the full per-batch
// xs/xe arrays in LDS (cheap), then counts pairs for its 128-slot t-chunk.
__global__ __launch_bounds__(128) void overlap_kernel(const int* __restrict__ pred,
                                                      const int* __restrict__ sizes,
                                                      int* __restrict__ counts) {
    const int b     = blockIdx.x >> 3;
    const int chunk = blockIdx.x & 7;
    const int tid   = threadIdx.x;

    __shared__ int perm_s[T];
    __shared__ int se_s[T];   // sizes, then xe after phase C
    __shared__ int xs_s[T];

    const int* prow = pred  + b * T;
    const int* srow = sizes + b * V;

    for (int t = tid; t < T; t += 128) {
        const int p = prow[t];
        perm_s[t] = p;
        se_s[t]   = srow[p];          // sz[b,t] = sizes[b, perm[b,t]]
    }
    __syncthreads();

    // offset o_t: clamped max-suffix-sum over the maximal run of equal stations
    // ending at t-1 (o resets to 0 whenever the station changes).
    for (int t = tid; t < T; t += 128) {
        const int p = perm_s[t];
        int acc = 0, o = 0;
        for (int j = t - 1; j >= 0 && perm_s[j] == p; --j) {
            acc += se_s[j] - TAKT;
            if (acc > o) o = acc;
        }
        xs_s[t] = t * TAKT + o;
    }
    __syncthreads();
    for (int t = tid; t < T; t += 128) se_s[t] += xs_s[t];   // xe = xs + sz
    __syncthreads();

    // count pairs (t, t'<t): same station && xs_t < xe_t' && xe_t > xs_t'
    const int t = chunk * 128 + tid;
    const int p = perm_s[t], a = xs_s[t], e = se_s[t];
    int cnt = 0;
    for (int tp = 0; tp < t; ++tp) {
        cnt += (int)((perm_s[tp] == p) & (a < se_s[tp]) & (e > xs_s[tp]));
    }

    __shared__ int scnt[128];
    scnt[tid] = cnt;
    __syncthreads();
    for (int off = 64; off > 0; off >>= 1) {
        if (tid < off) scnt[tid] += scnt[tid + off];
        __syncthreads();
    }
    if (tid == 0) counts[blockIdx.x] = scnt[0];
}

// ---------------- Kernel 3: final deterministic reduction ----------------
__global__ __launch_bounds__(256) void final_kernel(const float* __restrict__ rowloss,
                                                    const int* __restrict__ counts,
                                                    float* __restrict__ out) {
    const int tid = threadIdx.x;
    double acc = 0.0;
    for (int i = tid; i < B * T; i += 256) acc += (double)rowloss[i];

    __shared__ double sacc[256];
    __shared__ int    scnt[256];
    sacc[tid] = acc;
    scnt[tid] = counts[tid];          // exactly 256 chunk counts
    __syncthreads();
    for (int off = 128; off > 0; off >>= 1) {
        if (tid < off) { sacc[tid] += sacc[tid + off]; scnt[tid] += scnt[tid + off]; }
        __syncthreads();
    }
    if (tid == 0) {
        out[0] = (float)(sacc[0] / (double)(B * T)) + (float)scnt[0] / (float)B;
    }
}

extern "C" void kernel_launch(void* const* d_in, const int* in_sizes, int n_in,
                              void* d_out, int out_size, void* d_ws, size_t ws_size,
                              hipStream_t stream) {
    const float* logits = (const float*)d_in[0];   // [B,T,V] f32
    const int*   tgt    = (const int*)d_in[1];     // [B,T]   i32
    const int*   sizes  = (const int*)d_in[2];     // [B,V]   i32
    float* out = (float*)d_out;

    float* rowloss = (float*)d_ws;                            // B*T floats
    int*   pred    = (int*)((char*)d_ws + (size_t)B * T * 4); // B*T ints
    int*   counts  = (int*)((char*)d_ws + (size_t)B * T * 8); // 256 ints

    row_kernel<<<B * T, 256, 0, stream>>>(logits, tgt, rowloss, pred);
    overlap_kernel<<<B * 8, 128, 0, stream>>>(pred, sizes, counts);
    final_kernel<<<1, 256, 0, stream>>>(rowloss, counts, out);
}

// Round 2
// 110.147 us; speedup vs baseline: 1.1758x; 1.1758x over previous
//
#include <hip/hip_runtime.h>

#define TAKT 700
#define B 32
#define T 1024
#define V 1024

// ---------------- Kernel 1: per-row log-softmax CE term + argmax ----------------
// One WAVE (64 lanes) per row; 4 rows per 256-thread block. No LDS, no barriers.
// Lane holds 16 elems as 4 coalesced float4 loads (elem idx = 4*lane + 256*k + j).
__global__ __launch_bounds__(256) void row_kernel(const float* __restrict__ logits,
                                                  const int* __restrict__ tgt,
                                                  float* __restrict__ rowloss,
                                                  int* __restrict__ pred) {
    const int wave = threadIdx.x >> 6;
    const int lane = threadIdx.x & 63;
    const int row  = blockIdx.x * 4 + wave;       // 0..B*T-1

    const float4* base = reinterpret_cast<const float4*>(logits + (size_t)row * V);
    float4 v[4];
#pragma unroll
    for (int k = 0; k < 4; ++k) v[k] = base[lane + 64 * k];

    // local max + first index (element order within lane is ascending in k,j)
    float m = v[0].x; int mi = lane * 4;
#pragma unroll
    for (int k = 0; k < 4; ++k) {
        const float* q = reinterpret_cast<const float*>(&v[k]);
#pragma unroll
        for (int j = 0; j < 4; ++j) {
            const float x = q[j];
            const int idx = lane * 4 + k * 256 + j;
            if (x > m) { m = x; mi = idx; }
        }
    }

    // wave reduce: (max, min-index-at-max) — first-match argmax semantics
#pragma unroll
    for (int off = 32; off > 0; off >>= 1) {
        const float om = __shfl_xor(m, off, 64);
        const int   oi = __shfl_xor(mi, off, 64);
        if (om > m || (om == m && oi < mi)) { m = om; mi = oi; }
    }

    // sum of exp(x - max)
    float s = 0.f;
#pragma unroll
    for (int k = 0; k < 4; ++k) {
        const float* q = reinterpret_cast<const float*>(&v[k]);
#pragma unroll
        for (int j = 0; j < 4; ++j) s += __expf(q[j] - m);
    }
#pragma unroll
    for (int off = 32; off > 0; off >>= 1) s += __shfl_xor(s, off, 64);

    // x[tgt]: tgt is wave-uniform; pick (k,j) via uniform selects, shfl from owner
    const int tg = tgt[row];
    const int q4 = tg >> 2;             // which float4 slot (0..255)
    const int srcLane = q4 & 63;
    const int kk = q4 >> 6;
    const int jj = tg & 3;
    const float4 vk = (kk == 0) ? v[0] : (kk == 1) ? v[1] : (kk == 2) ? v[2] : v[3];
    const float xl = (jj == 0) ? vk.x : (jj == 1) ? vk.y : (jj == 2) ? vk.z : vk.w;
    const float xt = __shfl(xl, srcLane, 64);

    if (lane == 0) {
        rowloss[row] = logf(s) + m - xt;   // -(xt - max - logZ)
        pred[row]    = mi;
    }
}

// ---------------- Kernel 2: overlap penalty ----------------
// grid = B*8 blocks: block (b, chunk). Each block rebuilds the full per-batch
// xs/xe arrays in LDS (cheap), then counts pairs for its 128-slot t-chunk.
__global__ __launch_bounds__(128) void overlap_kernel(const int* __restrict__ pred,
                                                      const int* __restrict__ sizes,
                                                      int* __restrict__ counts) {
    const int b     = blockIdx.x >> 3;
    const int chunk = blockIdx.x & 7;
    const int tid   = threadIdx.x;

    __shared__ int perm_s[T];
    __shared__ int se_s[T];   // sizes, then xe after phase C
    __shared__ int xs_s[T];

    const int* prow = pred  + b * T;
    const int* srow = sizes + b * V;

    for (int t = tid; t < T; t += 128) {
        const int p = prow[t];
        perm_s[t] = p;
        se_s[t]   = srow[p];          // sz[b,t] = sizes[b, perm[b,t]]
    }
    __syncthreads();

    // offset o_t: clamped max-suffix-sum over the maximal run of equal stations
    // ending at t-1 (o resets to 0 whenever the station changes).
    for (int t = tid; t < T; t += 128) {
        const int p = perm_s[t];
        int acc = 0, o = 0;
        for (int j = t - 1; j >= 0 && perm_s[j] == p; --j) {
            acc += se_s[j] - TAKT;
            if (acc > o) o = acc;
        }
        xs_s[t] = t * TAKT + o;
    }
    __syncthreads();
    for (int t = tid; t < T; t += 128) se_s[t] += xs_s[t];   // xe = xs + sz
    __syncthreads();

    // count pairs (t, t'<t): same station && xs_t < xe_t' && xe_t > xs_t'
    const int t = chunk * 128 + tid;
    const int p = perm_s[t], a = xs_s[t], e = se_s[t];
    int cnt = 0;
    for (int tp = 0; tp < t; ++tp) {
        cnt += (int)((perm_s[tp] == p) & (a < se_s[tp]) & (e > xs_s[tp]));
    }

    __shared__ int scnt[128];
    scnt[tid] = cnt;
    __syncthreads();
    for (int off = 64; off > 0; off >>= 1) {
        if (tid < off) scnt[tid] += scnt[tid + off];
        __syncthreads();
    }
    if (tid == 0) counts[blockIdx.x] = scnt[0];
}

// ---------------- Kernel 3: final deterministic reduction ----------------
__global__ __launch_bounds__(256) void final_kernel(const float* __restrict__ rowloss,
                                                    const int* __restrict__ counts,
                                                    float* __restrict__ out) {
    const int tid = threadIdx.x;
    double acc = 0.0;
    const float4* rl4 = reinterpret_cast<const float4*>(rowloss);
    for (int i = tid; i < (B * T) / 4; i += 256) {
        const float4 r = rl4[i];
        acc += (double)r.x + (double)r.y + (double)r.z + (double)r.w;
    }

    __shared__ double sacc[256];
    __shared__ int    scnt[256];
    sacc[tid] = acc;
    scnt[tid] = counts[tid];          // exactly 256 chunk counts
    __syncthreads();
    for (int off = 128; off > 0; off >>= 1) {
        if (tid < off) { sacc[tid] += sacc[tid + off]; scnt[tid] += scnt[tid + off]; }
        __syncthreads();
    }
    if (tid == 0) {
        out[0] = (float)(sacc[0] / (double)(B * T)) + (float)scnt[0] / (float)B;
    }
}

extern "C" void kernel_launch(void* const* d_in, const int* in_sizes, int n_in,
                              void* d_out, int out_size, void* d_ws, size_t ws_size,
                              hipStream_t stream) {
    const float* logits = (const float*)d_in[0];   // [B,T,V] f32
    const int*   tgt    = (const int*)d_in[1];     // [B,T]   i32
    const int*   sizes  = (const int*)d_in[2];     // [B,V]   i32
    float* out = (float*)d_out;

    float* rowloss = (float*)d_ws;                            // B*T floats
    int*   pred    = (int*)((char*)d_ws + (size_t)B * T * 4); // B*T ints
    int*   counts  = (int*)((char*)d_ws + (size_t)B * T * 8); // 256 ints

    row_kernel<<<(B * T) / 4, 256, 0, stream>>>(logits, tgt, rowloss, pred);
    overlap_kernel<<<B * 8, 128, 0, stream>>>(pred, sizes, counts);
    final_kernel<<<1, 256, 0, stream>>>(rowloss, counts, out);
}

// Round 3
// 73.211 us; speedup vs baseline: 1.7689x; 1.5045x over previous
//
#include <hip/hip_runtime.h>

#define TAKT 700
#define B 32
#define T 1024
#define V 1024

// ---------------- Kernel 1: per-row log-softmax CE term + argmax ----------------
// One WAVE (64 lanes) per row; 4 rows per 256-thread block. No LDS, no barriers.
__global__ __launch_bounds__(256) void row_kernel(const float* __restrict__ logits,
                                                  const int* __restrict__ tgt,
                                                  float* __restrict__ rowloss,
                                                  int* __restrict__ pred) {
    const int wave = threadIdx.x >> 6;
    const int lane = threadIdx.x & 63;
    const int row  = blockIdx.x * 4 + wave;       // 0..B*T-1

    const float4* base = reinterpret_cast<const float4*>(logits + (size_t)row * V);
    float4 v[4];
#pragma unroll
    for (int k = 0; k < 4; ++k) v[k] = base[lane + 64 * k];

    // local max + first index
    float m = v[0].x; int mi = lane * 4;
#pragma unroll
    for (int k = 0; k < 4; ++k) {
        const float* q = reinterpret_cast<const float*>(&v[k]);
#pragma unroll
        for (int j = 0; j < 4; ++j) {
            const float x = q[j];
            const int idx = lane * 4 + k * 256 + j;
            if (x > m) { m = x; mi = idx; }
        }
    }

    // wave reduce: (max, min-index-at-max) — first-match argmax semantics
#pragma unroll
    for (int off = 32; off > 0; off >>= 1) {
        const float om = __shfl_xor(m, off, 64);
        const int   oi = __shfl_xor(mi, off, 64);
        if (om > m || (om == m && oi < mi)) { m = om; mi = oi; }
    }

    // sum of exp(x - max)
    float s = 0.f;
#pragma unroll
    for (int k = 0; k < 4; ++k) {
        const float* q = reinterpret_cast<const float*>(&v[k]);
#pragma unroll
        for (int j = 0; j < 4; ++j) s += __expf(q[j] - m);
    }
#pragma unroll
    for (int off = 32; off > 0; off >>= 1) s += __shfl_xor(s, off, 64);

    // x[tgt]: tgt is wave-uniform; uniform selects + one shfl from owner lane
    const int tg = tgt[row];
    const int q4 = tg >> 2;
    const int srcLane = q4 & 63;
    const int kk = q4 >> 6;
    const int jj = tg & 3;
    const float4 vk = (kk == 0) ? v[0] : (kk == 1) ? v[1] : (kk == 2) ? v[2] : v[3];
    const float xl = (jj == 0) ? vk.x : (jj == 1) ? vk.y : (jj == 2) ? vk.z : vk.w;
    const float xt = __shfl(xl, srcLane, 64);

    if (lane == 0) {
        rowloss[row] = logf(s) + m - xt;
        pred[row]    = mi;
    }
}

// ---------------- Kernel 2: overlap penalty ----------------
// grid = B*16 blocks, 256 threads. Block (b, chunk) owns 64 t-slots; 4 threads
// share each t, splitting the tp<t loop stride-4. (xs,xe) packed as int2 so the
// inner loop is one ds_read_b64 + one ds_read_b32 (both wave-broadcast).
__global__ __launch_bounds__(256) void overlap_kernel(const int* __restrict__ pred,
                                                      const int* __restrict__ sizes,
                                                      int* __restrict__ counts) {
    const int b     = blockIdx.x >> 4;
    const int chunk = blockIdx.x & 15;
    const int tid   = threadIdx.x;

    __shared__ int  perm_s[T];
    __shared__ int  sz_s[T];
    __shared__ int2 iv_s[T];     // (xs, xe)

    const int* prow = pred  + b * T;
    const int* srow = sizes + b * V;

    for (int t = tid; t < T; t += 256) {
        const int p = prow[t];
        perm_s[t] = p;
        sz_s[t]   = srow[p];          // sz[b,t] = sizes[b, perm[b,t]]
    }
    __syncthreads();

    // o_t = clamped max-suffix-sum of (sz - takt) over the run of equal
    // stations ending at t-1 (resets on station change).
    for (int t = tid; t < T; t += 256) {
        const int p = perm_s[t];
        int acc = 0, o = 0;
        for (int j = t - 1; j >= 0 && perm_s[j] == p; --j) {
            acc += sz_s[j] - TAKT;
            if (acc > o) o = acc;
        }
        const int xs = t * TAKT + o;
        iv_s[t] = make_int2(xs, xs + sz_s[t]);
    }
    __syncthreads();

    // count pairs (t, tp<t): same station && xs_t < xe_tp && xe_t > xs_tp
    const int t   = chunk * 64 + (tid & 63);
    const int sub = tid >> 6;                    // 0..3, uniform per wave
    const int p = perm_s[t];
    const int2 me = iv_s[t];
    int cnt = 0;
    for (int tp = sub; tp < t; tp += 4) {
        const int2 iv = iv_s[tp];
        cnt += (int)((perm_s[tp] == p) & (me.x < iv.y) & (me.y > iv.x));
    }

    __shared__ int scnt[256];
    scnt[tid] = cnt;
    __syncthreads();
    for (int off = 128; off > 0; off >>= 1) {
        if (tid < off) scnt[tid] += scnt[tid + off];
        __syncthreads();
    }
    if (tid == 0) counts[blockIdx.x] = scnt[0];
}

// ---------------- Kernel 3: final deterministic reduction ----------------
__global__ __launch_bounds__(256) void final_kernel(const float* __restrict__ rowloss,
                                                    const int* __restrict__ counts,
                                                    float* __restrict__ out) {
    const int tid = threadIdx.x;
    double acc = 0.0;
    const float4* rl4 = reinterpret_cast<const float4*>(rowloss);
    for (int i = tid; i < (B * T) / 4; i += 256) {
        const float4 r = rl4[i];
        acc += (double)r.x + (double)r.y + (double)r.z + (double)r.w;
    }

    __shared__ double sacc[256];
    __shared__ int    scnt[256];
    sacc[tid] = acc;
    scnt[tid] = counts[tid] + counts[tid + 256];   // 512 chunk counts
    __syncthreads();
    for (int off = 128; off > 0; off >>= 1) {
        if (tid < off) { sacc[tid] += sacc[tid + off]; scnt[tid] += scnt[tid + off]; }
        __syncthreads();
    }
    if (tid == 0) {
        out[0] = (float)(sacc[0] / (double)(B * T)) + (float)scnt[0] / (float)B;
    }
}

extern "C" void kernel_launch(void* const* d_in, const int* in_sizes, int n_in,
                              void* d_out, int out_size, void* d_ws, size_t ws_size,
                              hipStream_t stream) {
    const float* logits = (const float*)d_in[0];   // [B,T,V] f32
    const int*   tgt    = (const int*)d_in[1];     // [B,T]   i32
    const int*   sizes  = (const int*)d_in[2];     // [B,V]   i32
    float* out = (float*)d_out;

    float* rowloss = (float*)d_ws;                            // B*T floats
    int*   pred    = (int*)((char*)d_ws + (size_t)B * T * 4); // B*T ints
    int*   counts  = (int*)((char*)d_ws + (size_t)B * T * 8); // 512 ints

    row_kernel<<<(B * T) / 4, 256, 0, stream>>>(logits, tgt, rowloss, pred);
    overlap_kernel<<<B * 16, 256, 0, stream>>>(pred, sizes, counts);
    final_kernel<<<1, 256, 0, stream>>>(rowloss, counts, out);
}

// Round 4
// 72.399 us; speedup vs baseline: 1.7888x; 1.0112x over previous
//
#include <hip/hip_runtime.h>

#define TAKT 700
#define B 32
#define T 1024
#define V 1024
#define BIGIDX 0x7fffffff

// ---------------- Kernel 1: per-row log-softmax CE term + argmax ----------------
// One WAVE per 2 rows (8 rows / 256-thread block): 8 float4 loads in flight,
// independent reduction chains interleaved for ILP. No LDS, no barriers.
__global__ __launch_bounds__(256) void row_kernel(const float* __restrict__ logits,
                                                  const int* __restrict__ tgt,
                                                  float* __restrict__ rowloss,
                                                  int* __restrict__ pred) {
    const int wave = threadIdx.x >> 6;
    const int lane = threadIdx.x & 63;
    const int row0 = blockIdx.x * 8 + wave * 2;
    const int row1 = row0 + 1;

    const float4* b0 = reinterpret_cast<const float4*>(logits + (size_t)row0 * V);
    const float4* b1 = reinterpret_cast<const float4*>(logits + (size_t)row1 * V);
    float4 v0[4], v1[4];
#pragma unroll
    for (int k = 0; k < 4; ++k) { v0[k] = b0[lane + 64 * k]; v1[k] = b1[lane + 64 * k]; }

    // local max (float only)
    float m0 = v0[0].x, m1 = v1[0].x;
#pragma unroll
    for (int k = 0; k < 4; ++k) {
        const float* q0 = reinterpret_cast<const float*>(&v0[k]);
        const float* q1 = reinterpret_cast<const float*>(&v1[k]);
#pragma unroll
        for (int j = 0; j < 4; ++j) { m0 = fmaxf(m0, q0[j]); m1 = fmaxf(m1, q1[j]); }
    }
    // wave max reduce, two independent chains interleaved
#pragma unroll
    for (int off = 32; off > 0; off >>= 1) {
        m0 = fmaxf(m0, __shfl_xor(m0, off, 64));
        m1 = fmaxf(m1, __shfl_xor(m1, off, 64));
    }

    // exp-sums and first-argmax indices (exact equality with reduced max)
    float s0 = 0.f, s1 = 0.f;
    int i0 = BIGIDX, i1 = BIGIDX;
#pragma unroll
    for (int k = 0; k < 4; ++k) {
        const float* q0 = reinterpret_cast<const float*>(&v0[k]);
        const float* q1 = reinterpret_cast<const float*>(&v1[k]);
#pragma unroll
        for (int j = 0; j < 4; ++j) {
            const int idx = lane * 4 + k * 256 + j;
            s0 += __expf(q0[j] - m0);
            s1 += __expf(q1[j] - m1);
            i0 = min(i0, (q0[j] == m0) ? idx : BIGIDX);
            i1 = min(i1, (q1[j] == m1) ? idx : BIGIDX);
        }
    }
    // four independent reduction chains interleaved
#pragma unroll
    for (int off = 32; off > 0; off >>= 1) {
        s0 += __shfl_xor(s0, off, 64);
        s1 += __shfl_xor(s1, off, 64);
        i0 = min(i0, __shfl_xor(i0, off, 64));
        i1 = min(i1, __shfl_xor(i1, off, 64));
    }

    // x[tgt] for both rows: wave-uniform selects + one shfl each
    const int tg0 = tgt[row0], tg1 = tgt[row1];
    {
        const int q4 = tg0 >> 2, kk = q4 >> 6, jj = tg0 & 3;
        const float4 vk = (kk == 0) ? v0[0] : (kk == 1) ? v0[1] : (kk == 2) ? v0[2] : v0[3];
        const float xl = (jj == 0) ? vk.x : (jj == 1) ? vk.y : (jj == 2) ? vk.z : vk.w;
        const float xt = __shfl(xl, q4 & 63, 64);
        if (lane == 0) { rowloss[row0] = logf(s0) + m0 - xt; pred[row0] = i0; }
    }
    {
        const int q4 = tg1 >> 2, kk = q4 >> 6, jj = tg1 & 3;
        const float4 vk = (kk == 0) ? v1[0] : (kk == 1) ? v1[1] : (kk == 2) ? v1[2] : v1[3];
        const float xl = (jj == 0) ? vk.x : (jj == 1) ? vk.y : (jj == 2) ? vk.z : vk.w;
        const float xt = __shfl(xl, q4 & 63, 64);
        if (lane == 0) { rowloss[row1] = logf(s1) + m1 - xt; pred[row1] = i1; }
    }
}

// ---------------- Kernel 2: overlap penalty ----------------
// grid = B*32 blocks, 256 threads. Block (b, chunk) owns 32 t-slots; 8 threads
// share each t, splitting the tp<t loop stride-8. LDS reads are (half-wave)
// broadcasts: at most 2 distinct addresses per wave instr -> conflict-free.
__global__ __launch_bounds__(256) void overlap_kernel(const int* __restrict__ pred,
                                                      const int* __restrict__ sizes,
                                                      int* __restrict__ counts) {
    const int b     = blockIdx.x >> 5;
    const int chunk = blockIdx.x & 31;
    const int tid   = threadIdx.x;

    __shared__ int  perm_s[T];
    __shared__ int  sz_s[T];
    __shared__ int2 iv_s[T];     // (xs, xe)

    const int* prow = pred  + b * T;
    const int* srow = sizes + b * V;

    for (int t = tid; t < T; t += 256) {
        const int p = prow[t];
        perm_s[t] = p;
        sz_s[t]   = srow[p];          // sz[b,t] = sizes[b, perm[b,t]]
    }
    __syncthreads();

    // o_t = clamped max-suffix-sum of (sz - takt) over the run of equal
    // stations ending at t-1 (resets on station change). Expected O(1) walk.
    for (int t = tid; t < T; t += 256) {
        const int p = perm_s[t];
        int acc = 0, o = 0;
        for (int j = t - 1; j >= 0 && perm_s[j] == p; --j) {
            acc += sz_s[j] - TAKT;
            if (acc > o) o = acc;
        }
        const int xs = t * TAKT + o;
        iv_s[t] = make_int2(xs, xs + sz_s[t]);
    }
    __syncthreads();

    // count pairs (t, tp<t): same station && xs_t < xe_tp && xe_t > xs_tp
    const int t   = chunk * 32 + (tid & 31);
    const int sub = tid >> 5;                    // 0..7
    const int p = perm_s[t];
    const int2 me = iv_s[t];
    int cnt = 0;
    for (int tp = sub; tp < t; tp += 8) {
        const int2 iv = iv_s[tp];
        cnt += (int)((perm_s[tp] == p) & (me.x < iv.y) & (me.y > iv.x));
    }

    __shared__ int scnt[256];
    scnt[tid] = cnt;
    __syncthreads();
    for (int off = 128; off > 0; off >>= 1) {
        if (tid < off) scnt[tid] += scnt[tid + off];
        __syncthreads();
    }
    if (tid == 0) counts[blockIdx.x] = scnt[0];
}

// ---------------- Kernel 3: final deterministic reduction ----------------
__global__ __launch_bounds__(256) void final_kernel(const float* __restrict__ rowloss,
                                                    const int* __restrict__ counts,
                                                    float* __restrict__ out) {
    const int tid = threadIdx.x;
    double acc = 0.0;
    const float4* rl4 = reinterpret_cast<const float4*>(rowloss);
    for (int i = tid; i < (B * T) / 4; i += 256) {
        const float4 r = rl4[i];
        acc += (double)r.x + (double)r.y + (double)r.z + (double)r.w;
    }

    __shared__ double sacc[256];
    __shared__ int    scnt[256];
    sacc[tid] = acc;
    scnt[tid] = counts[tid] + counts[tid + 256] + counts[tid + 512] + counts[tid + 768];
    __syncthreads();
    for (int off = 128; off > 0; off >>= 1) {
        if (tid < off) { sacc[tid] += sacc[tid + off]; scnt[tid] += scnt[tid + off]; }
        __syncthreads();
    }
    if (tid == 0) {
        out[0] = (float)(sacc[0] / (double)(B * T)) + (float)scnt[0] / (float)B;
    }
}

extern "C" void kernel_launch(void* const* d_in, const int* in_sizes, int n_in,
                              void* d_out, int out_size, void* d_ws, size_t ws_size,
                              hipStream_t stream) {
    const float* logits = (const float*)d_in[0];   // [B,T,V] f32
    const int*   tgt    = (const int*)d_in[1];     // [B,T]   i32
    const int*   sizes  = (const int*)d_in[2];     // [B,V]   i32
    float* out = (float*)d_out;

    float* rowloss = (float*)d_ws;                            // B*T floats
    int*   pred    = (int*)((char*)d_ws + (size_t)B * T * 4); // B*T ints
    int*   counts  = (int*)((char*)d_ws + (size_t)B * T * 8); // 1024 ints

    row_kernel<<<(B * T) / 8, 256, 0, stream>>>(logits, tgt, rowloss, pred);
    overlap_kernel<<<B * 32, 256, 0, stream>>>(pred, sizes, counts);
    final_kernel<<<1, 256, 0, stream>>>(rowloss, counts, out);
}

// Round 5
// 72.127 us; speedup vs baseline: 1.7955x; 1.0038x over previous
//
#include <hip/hip_runtime.h>

#define TAKT 700
#define B 32
#define T 1024
#define V 1024
#define BIGIDX 0x7fffffff

// ---------------- Kernel 1: per-row log-softmax CE term + argmax ----------------
// One WAVE per 2 rows (8 rows / 256-thread block): 8 float4 loads in flight,
// independent reduction chains interleaved for ILP. No LDS, no barriers.
// __launch_bounds__(256, 4): cap at 4 waves/EU -> 128 VGPR budget. Without the
// second arg the compiler targeted 32 VGPRs and SPILLED the 32 registers of
// live float4 data to scratch (R4 profile: VGPR_Count=32, 984 GB/s, 77 us).
__global__ __launch_bounds__(256, 4) void row_kernel(const float* __restrict__ logits,
                                                     const int* __restrict__ tgt,
                                                     float* __restrict__ rowloss,
                                                     int* __restrict__ pred) {
    const int wave = threadIdx.x >> 6;
    const int lane = threadIdx.x & 63;
    const int row0 = blockIdx.x * 8 + wave * 2;
    const int row1 = row0 + 1;

    const float4* b0 = reinterpret_cast<const float4*>(logits + (size_t)row0 * V);
    const float4* b1 = reinterpret_cast<const float4*>(logits + (size_t)row1 * V);
    float4 v0[4], v1[4];
#pragma unroll
    for (int k = 0; k < 4; ++k) { v0[k] = b0[lane + 64 * k]; v1[k] = b1[lane + 64 * k]; }

    // local max (float only)
    float m0 = v0[0].x, m1 = v1[0].x;
#pragma unroll
    for (int k = 0; k < 4; ++k) {
        const float* q0 = reinterpret_cast<const float*>(&v0[k]);
        const float* q1 = reinterpret_cast<const float*>(&v1[k]);
#pragma unroll
        for (int j = 0; j < 4; ++j) { m0 = fmaxf(m0, q0[j]); m1 = fmaxf(m1, q1[j]); }
    }
    // wave max reduce, two independent chains interleaved
#pragma unroll
    for (int off = 32; off > 0; off >>= 1) {
        m0 = fmaxf(m0, __shfl_xor(m0, off, 64));
        m1 = fmaxf(m1, __shfl_xor(m1, off, 64));
    }

    // exp-sums and first-argmax indices (exact equality with reduced max)
    float s0 = 0.f, s1 = 0.f;
    int i0 = BIGIDX, i1 = BIGIDX;
#pragma unroll
    for (int k = 0; k < 4; ++k) {
        const float* q0 = reinterpret_cast<const float*>(&v0[k]);
        const float* q1 = reinterpret_cast<const float*>(&v1[k]);
#pragma unroll
        for (int j = 0; j < 4; ++j) {
            const int idx = lane * 4 + k * 256 + j;
            s0 += __expf(q0[j] - m0);
            s1 += __expf(q1[j] - m1);
            i0 = min(i0, (q0[j] == m0) ? idx : BIGIDX);
            i1 = min(i1, (q1[j] == m1) ? idx : BIGIDX);
        }
    }
    // four independent reduction chains interleaved
#pragma unroll
    for (int off = 32; off > 0; off >>= 1) {
        s0 += __shfl_xor(s0, off, 64);
        s1 += __shfl_xor(s1, off, 64);
        i0 = min(i0, __shfl_xor(i0, off, 64));
        i1 = min(i1, __shfl_xor(i1, off, 64));
    }

    // x[tgt] for both rows: wave-uniform selects + one shfl each
    const int tg0 = tgt[row0], tg1 = tgt[row1];
    {
        const int q4 = tg0 >> 2, kk = q4 >> 6, jj = tg0 & 3;
        const float4 vk = (kk == 0) ? v0[0] : (kk == 1) ? v0[1] : (kk == 2) ? v0[2] : v0[3];
        const float xl = (jj == 0) ? vk.x : (jj == 1) ? vk.y : (jj == 2) ? vk.z : vk.w;
        const float xt = __shfl(xl, q4 & 63, 64);
        if (lane == 0) { rowloss[row0] = logf(s0) + m0 - xt; pred[row0] = i0; }
    }
    {
        const int q4 = tg1 >> 2, kk = q4 >> 6, jj = tg1 & 3;
        const float4 vk = (kk == 0) ? v1[0] : (kk == 1) ? v1[1] : (kk == 2) ? v1[2] : v1[3];
        const float xl = (jj == 0) ? vk.x : (jj == 1) ? vk.y : (jj == 2) ? vk.z : vk.w;
        const float xt = __shfl(xl, q4 & 63, 64);
        if (lane == 0) { rowloss[row1] = logf(s1) + m1 - xt; pred[row1] = i1; }
    }
}

// ---------------- Kernel 2: overlap penalty ----------------
// grid = B*32 blocks, 256 threads. Block (b, chunk) owns 32 t-slots; 8 threads
// share each t, splitting the tp<t loop stride-8.
__global__ __launch_bounds__(256) void overlap_kernel(const int* __restrict__ pred,
                                                      const int* __restrict__ sizes,
                                                      int* __restrict__ counts) {
    const int b     = blockIdx.x >> 5;
    const int chunk = blockIdx.x & 31;
    const int tid   = threadIdx.x;

    __shared__ int  perm_s[T];
    __shared__ int  sz_s[T];
    __shared__ int2 iv_s[T];     // (xs, xe)

    const int* prow = pred  + b * T;
    const int* srow = sizes + b * V;

    for (int t = tid; t < T; t += 256) {
        const int p = prow[t];
        perm_s[t] = p;
        sz_s[t]   = srow[p];          // sz[b,t] = sizes[b, perm[b,t]]
    }
    __syncthreads();

    // o_t = clamped max-suffix-sum of (sz - takt) over the run of equal
    // stations ending at t-1 (resets on station change). Expected O(1) walk.
    for (int t = tid; t < T; t += 256) {
        const int p = perm_s[t];
        int acc = 0, o = 0;
        for (int j = t - 1; j >= 0 && perm_s[j] == p; --j) {
            acc += sz_s[j] - TAKT;
            if (acc > o) o = acc;
        }
        const int xs = t * TAKT + o;
        iv_s[t] = make_int2(xs, xs + sz_s[t]);
    }
    __syncthreads();

    // count pairs (t, tp<t): same station && xs_t < xe_tp && xe_t > xs_tp
    const int t   = chunk * 32 + (tid & 31);
    const int sub = tid >> 5;                    // 0..7
    const int p = perm_s[t];
    const int2 me = iv_s[t];
    int cnt = 0;
    for (int tp = sub; tp < t; tp += 8) {
        const int2 iv = iv_s[tp];
        cnt += (int)((perm_s[tp] == p) & (me.x < iv.y) & (me.y > iv.x));
    }

    __shared__ int scnt[256];
    scnt[tid] = cnt;
    __syncthreads();
    for (int off = 128; off > 0; off >>= 1) {
        if (tid < off) scnt[tid] += scnt[tid + off];
        __syncthreads();
    }
    if (tid == 0) counts[blockIdx.x] = scnt[0];
}

// ---------------- Kernel 3: final deterministic reduction ----------------
__global__ __launch_bounds__(256) void final_kernel(const float* __restrict__ rowloss,
                                                    const int* __restrict__ counts,
                                                    float* __restrict__ out) {
    const int tid = threadIdx.x;
    double acc = 0.0;
    const float4* rl4 = reinterpret_cast<const float4*>(rowloss);
    for (int i = tid; i < (B * T) / 4; i += 256) {
        const float4 r = rl4[i];
        acc += (double)r.x + (double)r.y + (double)r.z + (double)r.w;
    }

    __shared__ double sacc[256];
    __shared__ int    scnt[256];
    sacc[tid] = acc;
    scnt[tid] = counts[tid] + counts[tid + 256] + counts[tid + 512] + counts[tid + 768];
    __syncthreads();
    for (int off = 128; off > 0; off >>= 1) {
        if (tid < off) { sacc[tid] += sacc[tid + off]; scnt[tid] += scnt[tid + off]; }
        __syncthreads();
    }
    if (tid == 0) {
        out[0] = (float)(sacc[0] / (double)(B * T)) + (float)scnt[0] / (float)B;
    }
}

extern "C" void kernel_launch(void* const* d_in, const int* in_sizes, int n_in,
                              void* d_out, int out_size, void* d_ws, size_t ws_size,
                              hipStream_t stream) {
    const float* logits = (const float*)d_in[0];   // [B,T,V] f32
    const int*   tgt    = (const int*)d_in[1];     // [B,T]   i32
    const int*   sizes  = (const int*)d_in[2];     // [B,V]   i32
    float* out = (float*)d_out;

    float* rowloss = (float*)d_ws;                            // B*T floats
    int*   pred    = (int*)((char*)d_ws + (size_t)B * T * 4); // B*T ints
    int*   counts  = (int*)((char*)d_ws + (size_t)B * T * 8); // 1024 ints

    row_kernel<<<(B * T) / 8, 256, 0, stream>>>(logits, tgt, rowloss, pred);
    overlap_kernel<<<B * 32, 256, 0, stream>>>(pred, sizes, counts);
    final_kernel<<<1, 256, 0, stream>>>(rowloss, counts, out);
}